// Round 3
// baseline (946.838 us; speedup 1.0000x reference)
//
#include <hip/hip_runtime.h>
#include <hip/hip_bf16.h>

// Problem constants (match reference setup_inputs)
constexpr int T = 8;
constexpr int R = 200000;
constexpr int D = 128;
constexpr int B = 2048;
constexpr int NUM_BAGS = T * B;            // 16384
constexpr int SEGS = 4;                    // segments per bag (one per half-wave)
constexpr long PART_STRIDE = (long)NUM_BAGS * D;  // floats per segment-plane

// Phase 1: one half-wave (32 lanes) per (bag, segment). Each lane owns a 16B
// chunk of the 512B row. Indices preloaded 8-deep, then 8 row gathers + 8
// scale/shift gathers issued back-to-back. Partial sums written to ws.
__global__ __launch_bounds__(256)
void qembag_partial_kernel(const int* __restrict__ indices,
                           const int* __restrict__ offsets,
                           const int* __restrict__ qweights,
                           const float* __restrict__ scale_shift,
                           float* __restrict__ ws) {
    const int task = (int)(blockIdx.x * 8 + (threadIdx.x >> 5));  // half-wave id
    const int sub  = (int)(threadIdx.x & 31);
    const int bag  = task >> 2;
    const int seg  = task & 3;
    if (bag >= NUM_BAGS) return;

    const int t = bag >> 11;  // bag / B

    const int start = offsets[bag];
    const int len   = offsets[bag + 1] - start;
    const int jlo   = start + ((len * seg) >> 2);
    const int jhi   = start + ((len * (seg + 1)) >> 2);
    const int slen  = jhi - jlo;
    const int C     = slen >> 3;  // full chunks of 8 lookups

    float acc0 = 0.f, acc1 = 0.f, acc2 = 0.f, acc3 = 0.f;
    float sshift = 0.f;  // sum of shifts; added to every dim at the end

    const long tbase = (long)t * R;
    const int4*   qw4 = (const int4*)qweights;      // row r -> qw4[r*32 + sub]
    const float2* ss2 = (const float2*)scale_shift; // row r -> ss2[r]

    for (int c = 0; c < C; ++c) {
        const int base = jlo + (c << 3);
        int idx[8];
#pragma unroll
        for (int k = 0; k < 8; ++k) idx[k] = indices[base + k];

        int4   q[8];
        float2 s[8];
#pragma unroll
        for (int k = 0; k < 8; ++k) {
            const long r = tbase + idx[k];
            q[k] = qw4[r * 32 + sub];
            s[k] = ss2[r];
        }

#pragma unroll
        for (int k = 0; k < 8; ++k) {
            const float sc = s[k].x;
            sshift += s[k].y;
            acc0 = fmaf((float)q[k].x, sc, acc0);
            acc1 = fmaf((float)q[k].y, sc, acc1);
            acc2 = fmaf((float)q[k].z, sc, acc2);
            acc3 = fmaf((float)q[k].w, sc, acc3);
        }
    }

    for (int j = jlo + (C << 3); j < jhi; ++j) {
        const long r = tbase + indices[j];
        const int4 q = qw4[r * 32 + sub];
        const float2 ss = ss2[r];
        sshift += ss.y;
        acc0 = fmaf((float)q.x, ss.x, acc0);
        acc1 = fmaf((float)q.y, ss.x, acc1);
        acc2 = fmaf((float)q.z, ss.x, acc2);
        acc3 = fmaf((float)q.w, ss.x, acc3);
    }

    float4 v = make_float4(acc0 + sshift, acc1 + sshift,
                           acc2 + sshift, acc3 + sshift);
    ((float4*)(ws + (long)seg * PART_STRIDE + (long)bag * D))[sub] = v;
}

// Phase 2: out[batch*(T*D) + t*D + d] = sum over 4 segment planes of
// ws[seg][t*B+batch][d]. Fully coalesced reads and writes.
__global__ __launch_bounds__(256)
void qembag_reduce_kernel(const float* __restrict__ ws,
                          float* __restrict__ out) {
    const int gid = (int)(blockIdx.x * 256 + threadIdx.x);  // batch*1024 + t*128 + d
    const int d     = gid & 127;
    const int t     = (gid >> 7) & 7;
    const int batch = gid >> 10;
    const long p = ((long)(t * B + batch)) * D + d;
    out[gid] = ws[p] + ws[PART_STRIDE + p] + ws[2 * PART_STRIDE + p]
             + ws[3 * PART_STRIDE + p];
}

extern "C" void kernel_launch(void* const* d_in, const int* in_sizes, int n_in,
                              void* d_out, int out_size, void* d_ws, size_t ws_size,
                              hipStream_t stream) {
    const int*   indices     = (const int*)d_in[0];
    const int*   offsets     = (const int*)d_in[1];
    const int*   qweights    = (const int*)d_in[2];
    const float* scale_shift = (const float*)d_in[3];
    float*       out         = (float*)d_out;
    float*       ws          = (float*)d_ws;

    // Phase 1: 65536 half-wave tasks, 8 per 256-thread block
    qembag_partial_kernel<<<NUM_BAGS * SEGS / 8, 256, 0, stream>>>(
        indices, offsets, qweights, scale_shift, ws);
    // Phase 2: 2M output elements
    qembag_reduce_kernel<<<NUM_BAGS * D / 256, 256, 0, stream>>>(ws, out);
}

// Round 5
// 928.869 us; speedup vs baseline: 1.0193x; 1.0193x over previous
//
#include <hip/hip_runtime.h>
#include <hip/hip_bf16.h>

// Problem constants (match reference setup_inputs)
constexpr int T = 8;
constexpr int R = 200000;
constexpr int D = 128;
constexpr int B = 2048;
constexpr int NUM_BAGS = T * B;  // 16384

// Native vector type so __builtin_nontemporal_load accepts it
typedef int iv4 __attribute__((ext_vector_type(4)));
typedef float fv2 __attribute__((ext_vector_type(2)));

// One 64-lane wave per bag; two half-waves own alternating lookups.
// Lane sub in a half-wave loads 16B at dim 4*sub -> each row read is one
// coalesced 32-lane x 16B = 512B transaction. 8-deep gather batching per
// half (16 rows in flight per wave). Non-temporal loads on the zero-reuse
// gathered rows; next chunk's indices prefetched behind the gathers.
__global__ __launch_bounds__(256)
void qembag_kernel(const int* __restrict__ indices,
                   const int* __restrict__ offsets,
                   const int* __restrict__ qweights,
                   const float* __restrict__ scale_shift,
                   float* __restrict__ out) {
    const int wave_id = (int)((blockIdx.x * blockDim.x + threadIdx.x) >> 6);
    if (wave_id >= NUM_BAGS) return;
    const int lane = (int)(threadIdx.x & 63);
    const int half = lane >> 5;   // which lookup of an interleaved pair
    const int sub  = lane & 31;   // 16B chunk within the 512B row

    const int bag   = wave_id;
    const int t     = bag >> 11;      // bag / B   (B = 2048)
    const int batch = bag & (B - 1);  // bag % B

    const int start = offsets[bag];
    const int end   = offsets[bag + 1];
    const int len   = end - start;
    const int C     = len >> 4;       // full chunks of 16 lookups (8 per half)

    float acc0 = 0.f, acc1 = 0.f, acc2 = 0.f, acc3 = 0.f;
    float sshift = 0.f;               // pooled shift, added to all dims at end

    const long tbase = (long)t * R;
    const iv4* qw4 = (const iv4*)qweights;       // row r -> qw4[r*32 + sub]
    const fv2* ss2 = (const fv2*)scale_shift;    // row r -> ss2[r]

    // prologue: preload chunk 0's indices
    int idxb[8];
    if (C > 0) {
#pragma unroll
        for (int k = 0; k < 8; ++k) idxb[k] = indices[start + half + 2 * k];
    }

    for (int c = 0; c < C; ++c) {
        // 1) issue all 16 gathers (8 rows + 8 scale/shift) back-to-back
        iv4 q[8];
        fv2 s[8];
#pragma unroll
        for (int k = 0; k < 8; ++k) {
            const long r = tbase + idxb[k];
            q[k] = __builtin_nontemporal_load(&qw4[r * 32 + sub]);
            s[k] = ss2[r];
        }

        // 2) prefetch next chunk's indices while gathers are in flight
        if (c + 1 < C) {
            const int nbase = start + ((c + 1) << 4) + half;
#pragma unroll
            for (int k = 0; k < 8; ++k) idxb[k] = indices[nbase + 2 * k];
        }

        // 3) accumulate (shift hoisted: pooled separately, added once)
#pragma unroll
        for (int k = 0; k < 8; ++k) {
            const float sc = s[k].x;
            sshift += s[k].y;
            acc0 = fmaf((float)q[k].x, sc, acc0);
            acc1 = fmaf((float)q[k].y, sc, acc1);
            acc2 = fmaf((float)q[k].z, sc, acc2);
            acc3 = fmaf((float)q[k].w, sc, acc3);
        }
    }

    // remainder (< 16 lookups), interleaved between halves as before
    for (int j = start + (C << 4) + half; j < end; j += 2) {
        const long r = tbase + indices[j];
        const iv4 q = __builtin_nontemporal_load(&qw4[r * 32 + sub]);
        const fv2 ss = ss2[r];
        sshift += ss.y;
        acc0 = fmaf((float)q.x, ss.x, acc0);
        acc1 = fmaf((float)q.y, ss.x, acc1);
        acc2 = fmaf((float)q.z, ss.x, acc2);
        acc3 = fmaf((float)q.w, ss.x, acc3);
    }

    acc0 += sshift; acc1 += sshift; acc2 += sshift; acc3 += sshift;

    // Fold the two half-wave partial sums: lane s += lane s+32
    acc0 += __shfl_down(acc0, 32);
    acc1 += __shfl_down(acc1, 32);
    acc2 += __shfl_down(acc2, 32);
    acc3 += __shfl_down(acc3, 32);

    if (half == 0) {
        float4 v = make_float4(acc0, acc1, acc2, acc3);
        ((float4*)(out + (long)batch * (T * D) + t * D))[sub] = v;
    }
}

extern "C" void kernel_launch(void* const* d_in, const int* in_sizes, int n_in,
                              void* d_out, int out_size, void* d_ws, size_t ws_size,
                              hipStream_t stream) {
    const int*   indices     = (const int*)d_in[0];
    const int*   offsets     = (const int*)d_in[1];
    const int*   qweights    = (const int*)d_in[2];
    const float* scale_shift = (const float*)d_in[3];
    float*       out         = (float*)d_out;

    // 4 waves per 256-thread block, one wave per bag
    const int blocks = NUM_BAGS / 4;  // 4096
    qembag_kernel<<<blocks, 256, 0, stream>>>(indices, offsets, qweights,
                                              scale_shift, out);
}